// Round 1
// 299.241 us; speedup vs baseline: 1.0318x; 1.0318x over previous
//
#include <hip/hip_runtime.h>

// Problem shape (fixed by setup_inputs): l=8, p=1, m=4096, n=1024.
// One thread owns one row of n=1024 floats and runs the sequential
// recurrence w[k] = w[k-1] + a/w[k-1] - b*x[k-1], w[0] = 1.
// Rows = l*m = 32768 -> 512 waves total (structural max parallelism:
// the recurrence is nonlinear, so it cannot be split within a row
// while staying bit-exact). Occupancy is therefore pinned at ~2
// waves/CU; the only latency-hiding available is ILP via a deep
// software pipeline of in-flight loads.

#define N_COLS 1024
#define CHUNK 16                  // floats per pipelined chunk (4 x float4)
#define NCHUNK (N_COLS / CHUNK)   // 64 chunks per row
#define DEPTH 8                   // pipeline depth: 7 chunks (28 KB/wave) in flight

__device__ __forceinline__ float stepf(float w, float x, float a, float b) {
    // Match numpy fp32 exactly: (w + (a/w)) - (b*x), round-to-nearest,
    // no fma contraction, IEEE divide.
    return __fsub_rn(__fadd_rn(w, __fdiv_rn(a, w)), __fmul_rn(b, x));
}

__device__ __forceinline__ void load_chunk(const float4* __restrict__ p, int j,
                                           float* __restrict__ x) {
#pragma unroll
    for (int q = 0; q < CHUNK / 4; ++q) {
        float4 t = p[j * (CHUNK / 4) + q];
        x[q * 4 + 0] = t.x;
        x[q * 4 + 1] = t.y;
        x[q * 4 + 2] = t.z;
        x[q * 4 + 3] = t.w;
    }
}

__device__ __forceinline__ void compute_store(float4* __restrict__ outr, int j,
                                              const float* __restrict__ x,
                                              float& w, float a, float b) {
    float o[CHUNK];
    // out[C*j + 0] = current w; out[C*j + i] = step using x[C*j + i - 1]
    o[0] = w;
#pragma unroll
    for (int i = 1; i < CHUNK; ++i) {
        w = stepf(w, x[i - 1], a, b);
        o[i] = w;
    }
    // advance across the chunk boundary (harmless extra step on last chunk)
    w = stepf(w, x[CHUNK - 1], a, b);

#pragma unroll
    for (int q = 0; q < CHUNK / 4; ++q) {
        float4 t;
        t.x = o[q * 4 + 0];
        t.y = o[q * 4 + 1];
        t.z = o[q * 4 + 2];
        t.w = o[q * 4 + 3];
        outr[j * (CHUNK / 4) + q] = t;
    }
}

__global__ __launch_bounds__(64) void DDK_77644418777662_kernel(
    const float* __restrict__ in, float* __restrict__ out,
    const float* __restrict__ alpha, const float* __restrict__ beta,
    int n_rows) {
    int row = blockIdx.x * 64 + threadIdx.x;
    if (row >= n_rows) return;

    const float a = alpha[0];
    const float b = beta[0];

    const float4* __restrict__ inr =
        reinterpret_cast<const float4*>(in + (size_t)row * N_COLS);
    float4* __restrict__ outr =
        reinterpret_cast<float4*>(out + (size_t)row * N_COLS);

    // Rotating register pipeline. Every index into buf[][] is a
    // compile-time constant (k is from a fully-unrolled loop), so the
    // whole thing lives in VGPRs (rule: runtime-indexed arrays spill).
    // ~128 VGPRs for buffers is free: occupancy is thread-limited at
    // 2 waves/CU, unchanged up to 256 VGPRs.
    float buf[DEPTH][CHUNK];
    float w = 1.0f;

    // Prologue: fill DEPTH-1 = 7 chunks (28 load instrs in flight, vmcnt<=63 ok).
#pragma unroll
    for (int k = 0; k < DEPTH - 1; ++k) load_chunk(inr, k, buf[k]);

    // Main loop: 8 groups of 8 chunks. In steady state, the load for
    // chunk j+7 issues just before the compute of chunk j, keeping
    // 7 chunks x 4 KB = 28 KB per wave outstanding.
#pragma unroll 1
    for (int j = 0; j < NCHUNK; j += DEPTH) {
#pragma unroll
        for (int k = 0; k < DEPTH; ++k) {
            int jn = j + k + DEPTH - 1;
            // Slot that will hold chunk jn: (jn % DEPTH) == (k+DEPTH-1)%DEPTH.
            if (jn < NCHUNK) load_chunk(inr, jn, buf[(k + DEPTH - 1) % DEPTH]);
            compute_store(outr, j + k, buf[k], w, a, b);
        }
    }
}

extern "C" void kernel_launch(void* const* d_in, const int* in_sizes, int n_in,
                              void* d_out, int out_size, void* d_ws, size_t ws_size,
                              hipStream_t stream) {
    const float* in = (const float*)d_in[0];
    const float* alpha = (const float*)d_in[1];
    const float* beta = (const float*)d_in[2];
    float* out = (float*)d_out;

    int total = in_sizes[0];           // l*p*m*n = 33554432
    int n_rows = total / N_COLS;       // 32768

    dim3 grid((n_rows + 63) / 64);
    dim3 block(64);
    DDK_77644418777662_kernel<<<grid, block, 0, stream>>>(in, out, alpha, beta,
                                                          n_rows);
}